// Round 6
// baseline (974.663 us; speedup 1.0000x reference)
//
#include <hip/hip_runtime.h>
#include <hip/hip_bf16.h>

typedef unsigned int uint;
typedef unsigned short ushort;

#define B_ 4
#define T_ 4096
#define FIN 229
#define D_ 256
#define O_ 88
#define KW 31
#define G_ 8
#define LN_EPS 1e-5f

typedef __attribute__((ext_vector_type(8))) short short8;
typedef __attribute__((ext_vector_type(4))) float f32x4;

__device__ __forceinline__ ushort f2bf(float x) {
  uint u = __float_as_uint(x);
  uint r = (u + 0x7fffu + ((u >> 16) & 1u)) >> 16;
  return (ushort)r;
}
__device__ __forceinline__ float bflo(uint u) { return __uint_as_float(u << 16); }
__device__ __forceinline__ float bfhi(uint u) { return __uint_as_float(u & 0xffff0000u); }

// ---------- weights -> W2 [768][512] bf16: cols 0-255 hi, 256-511 lo ----------
__global__ __launch_bounds__(256) void conv_w2(const float* __restrict__ Wq,
                                               const float* __restrict__ Wk,
                                               const float* __restrict__ Wv,
                                               ushort* __restrict__ W2) {
  int d3 = blockIdx.x;          // 0..767
  int f = threadIdx.x;          // 0..255
  const float* src = (d3 < 256) ? Wq : (d3 < 512 ? Wk : Wv);
  int dr = d3 & 255;
  float x = (f < FIN) ? src[dr * FIN + f] : 0.f;
  ushort hi = f2bf(x);
  float rem = x - bflo((uint)hi);
  ushort lo = f2bf(rem);
  W2[(long)d3 * 512 + f] = hi;
  W2[(long)d3 * 512 + 256 + f] = lo;
}

// ---------- 3-term MFMA projection ----------
// K slots: seg0 (A hi * W hi), seg1 (A lo * W hi), seg2 (A hi * W lo)
// 24 steps of 32 slots; A converted from spec f32 on the fly.
#define KSTEPS 24
__global__ __launch_bounds__(256) void proj_mfma(const float* __restrict__ spec,
                                                 const ushort* __restrict__ W2,
                                                 float* __restrict__ qb,
                                                 ushort* __restrict__ khi,
                                                 ushort* __restrict__ klo,
                                                 ushort* __restrict__ vb) {
  __shared__ ushort As[128 * 40];
  __shared__ ushort Bs[128 * 40];
  int tid = threadIdx.x;
  int lane = tid & 63, w = tid >> 6;
  int bm = blockIdx.x, bn = blockIdx.y;
  int l15 = lane & 15, kg = lane >> 4;

  int rA = tid >> 1;            // 0..127
  int c0 = (tid & 1) * 16;      // 0 or 16
  const float* srow = spec + (long)(bm * 128 + rA) * FIN;
  const ushort* brow = W2 + (long)(bn * 128 + rA) * 512;

  f32x4 acc[2][8];
  #pragma unroll
  for (int mi = 0; mi < 2; ++mi)
    #pragma unroll
    for (int nf = 0; nf < 8; ++nf)
      acc[mi][nf] = (f32x4){0.f, 0.f, 0.f, 0.f};

  for (int s = 0; s < KSTEPS; ++s) {
    int seg = s >> 3;
    int f0 = (s & 7) * 32;
    int bcol = (seg == 2 ? 256 : 0) + f0;

    // A: load 16 spec f32, convert per segment
    float xs[16];
    #pragma unroll
    for (int u = 0; u < 16; ++u) {
      int f = f0 + c0 + u;
      xs[u] = (f < FIN) ? srow[f] : 0.f;
    }
    ushort hv[16];
    if (seg == 1) {
      #pragma unroll
      for (int u = 0; u < 16; ++u) {
        ushort hi = f2bf(xs[u]);
        hv[u] = f2bf(xs[u] - bflo((uint)hi));
      }
    } else {
      #pragma unroll
      for (int u = 0; u < 16; ++u) hv[u] = f2bf(xs[u]);
    }
    // B: this thread's 16 ushorts of the 32-wide k-slice
    uint4 b0 = *(const uint4*)(brow + bcol + c0);
    uint4 b1 = *(const uint4*)(brow + bcol + c0 + 8);

    __syncthreads();
    uint4 ap0, ap1;
    ap0.x = (uint)hv[0] | ((uint)hv[1] << 16);
    ap0.y = (uint)hv[2] | ((uint)hv[3] << 16);
    ap0.z = (uint)hv[4] | ((uint)hv[5] << 16);
    ap0.w = (uint)hv[6] | ((uint)hv[7] << 16);
    ap1.x = (uint)hv[8] | ((uint)hv[9] << 16);
    ap1.y = (uint)hv[10] | ((uint)hv[11] << 16);
    ap1.z = (uint)hv[12] | ((uint)hv[13] << 16);
    ap1.w = (uint)hv[14] | ((uint)hv[15] << 16);
    *(uint4*)(&As[rA * 40 + c0]) = ap0;
    *(uint4*)(&As[rA * 40 + c0 + 8]) = ap1;
    *(uint4*)(&Bs[rA * 40 + c0]) = b0;
    *(uint4*)(&Bs[rA * 40 + c0 + 8]) = b1;
    __syncthreads();

    short8 af[2];
    af[0] = *(const short8*)(&As[(w * 32 + l15) * 40 + kg * 8]);
    af[1] = *(const short8*)(&As[(w * 32 + 16 + l15) * 40 + kg * 8]);
    short8 bfr[8];
    #pragma unroll
    for (int nf = 0; nf < 8; ++nf)
      bfr[nf] = *(const short8*)(&Bs[(nf * 16 + l15) * 40 + kg * 8]);
    #pragma unroll
    for (int mi = 0; mi < 2; ++mi)
      #pragma unroll
      for (int nf = 0; nf < 8; ++nf)
        acc[mi][nf] = __builtin_amdgcn_mfma_f32_16x16x32_bf16(af[mi], bfr[nf], acc[mi][nf], 0, 0, 0);
  }

  #pragma unroll
  for (int mi = 0; mi < 2; ++mi)
    #pragma unroll
    for (int nf = 0; nf < 8; ++nf)
      #pragma unroll
      for (int ic = 0; ic < 4; ++ic) {
        int row = bm * 128 + w * 32 + mi * 16 + kg * 4 + ic;
        int col = bn * 128 + nf * 16 + l15;
        float val = acc[mi][nf][ic];
        if (bn < 2) {
          qb[(long)row * 256 + col] = val;
        } else if (bn < 4) {
          int c2 = col - 256;
          ushort hi = f2bf(val);
          ushort lo = f2bf(val - bflo((uint)hi));
          khi[(long)row * 256 + c2] = hi;
          klo[(long)row * 256 + c2] = lo;
        } else {
          vb[(long)row * 256 + (col - 512)] = f2bf(val);
        }
      }
}

// ---------- fused attention + LN + linear ----------
// LDS: kX @0 [47][256]b swz (24064) ; vS @24064 [47][256]b swz (24064)
//      qS @48128 [16][256]f (16384)
// overlays: aS @0 [16][8][32]b (8192, after pass2) ; hS @48128 [16][260]f (16640)
//           lwS @0 [88][264]b (46464, after PV)
#define KX_OFF 0
#define VS_OFF 24064
#define QS_OFF 48128
#define AS_OFF 0
#define HS_OFF 48128
#define LW_OFF 0
#define SM_BYTES 64768

__global__ __launch_bounds__(256) void attn3(
    const float* __restrict__ qb, const ushort* __restrict__ khi,
    const ushort* __restrict__ klo, const ushort* __restrict__ vb,
    const float* __restrict__ rel, const float* __restrict__ lng,
    const float* __restrict__ lnb, const float* __restrict__ lw,
    const float* __restrict__ lb,
    float* __restrict__ frame, float* __restrict__ attn) {
  __shared__ alignas(16) char sm[SM_BYTES];

  int tid = threadIdx.x;
  int b = blockIdx.y;
  int t0 = blockIdx.x * 16;
  long bT = (long)b * T_;
  int g = tid >> 5;
  int j = tid & 31;

  // ---- stage khi -> kX, v -> vS (47 rows, swizzled), q f32 -> qS ----
  for (int idx = tid; idx < 47 * 32; idx += 256) {
    int r = idx >> 5, c16 = idx & 31;
    int grow = t0 + r - 15;
    uint4 kv = {0u, 0u, 0u, 0u}, vv = {0u, 0u, 0u, 0u};
    if ((unsigned)grow < (unsigned)T_) {
      kv = *(const uint4*)(khi + (bT + grow) * 256 + c16 * 8);
      vv = *(const uint4*)(vb + (bT + grow) * 256 + c16 * 8);
    }
    int sw = (r * 512 + c16 * 16) ^ ((r & 7) << 4);
    *(uint4*)(sm + KX_OFF + sw) = kv;
    *(uint4*)(sm + VS_OFF + sw) = vv;
  }
  for (int idx = tid; idx < 16 * 64; idx += 256) {
    int r = idx >> 6, c4 = idx & 63;
    float4 qv = *(const float4*)(qb + (bT + t0 + r) * 256 + c4 * 4);
    *(float4*)(sm + QS_OFF + r * 1024 + c4 * 16) = qv;
  }
  // rel f32 into registers: relf[c] = rel[(g*32+c)*31 + j]
  float relf[32];
  #pragma unroll
  for (int c = 0; c < 32; ++c)
    relf[c] = (j < KW) ? rel[(g * 32 + c) * 31 + j] : 0.f;
  __syncthreads();

  float e[16];
  // ---- pass1: e = sum q*(khi + rel) ----
  #pragma unroll
  for (int i = 0; i < 16; ++i) {
    int row = i + j;
    float ee = 0.f;
    #pragma unroll
    for (int c = 0; c < 4; ++c) {
      uint4 kq = *(const uint4*)(sm + KX_OFF + ((row * 512 + g * 64 + c * 16) ^ ((row & 7) << 4)));
      float4 qa = *(const float4*)(sm + QS_OFF + i * 1024 + g * 128 + c * 32);
      float4 qc = *(const float4*)(sm + QS_OFF + i * 1024 + g * 128 + c * 32 + 16);
      ee += qa.x * (bflo(kq.x) + relf[c * 8 + 0]);
      ee += qa.y * (bfhi(kq.x) + relf[c * 8 + 1]);
      ee += qa.z * (bflo(kq.y) + relf[c * 8 + 2]);
      ee += qa.w * (bfhi(kq.y) + relf[c * 8 + 3]);
      ee += qc.x * (bflo(kq.z) + relf[c * 8 + 4]);
      ee += qc.y * (bfhi(kq.z) + relf[c * 8 + 5]);
      ee += qc.z * (bflo(kq.w) + relf[c * 8 + 6]);
      ee += qc.w * (bfhi(kq.w) + relf[c * 8 + 7]);
    }
    e[i] = ee;
  }
  __syncthreads();
  // ---- restage klo over kX ----
  for (int idx = tid; idx < 47 * 32; idx += 256) {
    int r = idx >> 5, c16 = idx & 31;
    int grow = t0 + r - 15;
    uint4 kv = {0u, 0u, 0u, 0u};
    if ((unsigned)grow < (unsigned)T_)
      kv = *(const uint4*)(klo + (bT + grow) * 256 + c16 * 8);
    *(uint4*)(sm + KX_OFF + ((r * 512 + c16 * 16) ^ ((r & 7) << 4))) = kv;
  }
  __syncthreads();
  // ---- pass2: e += sum q*klo ----
  #pragma unroll
  for (int i = 0; i < 16; ++i) {
    int row = i + j;
    float ee = e[i];
    #pragma unroll
    for (int c = 0; c < 4; ++c) {
      uint4 kq = *(const uint4*)(sm + KX_OFF + ((row * 512 + g * 64 + c * 16) ^ ((row & 7) << 4)));
      float4 qa = *(const float4*)(sm + QS_OFF + i * 1024 + g * 128 + c * 32);
      float4 qc = *(const float4*)(sm + QS_OFF + i * 1024 + g * 128 + c * 32 + 16);
      ee += qa.x * bflo(kq.x) + qa.y * bfhi(kq.x) + qa.z * bflo(kq.y) + qa.w * bfhi(kq.y);
      ee += qc.x * bflo(kq.z) + qc.y * bfhi(kq.z) + qc.z * bflo(kq.w) + qc.w * bfhi(kq.w);
    }
    e[i] = ee;
  }
  __syncthreads();   // all pass2 reads done; kX region may be overwritten (aS)

  // ---- softmax (lane j = kp), write attn f32 + aS bf16 ----
  ushort* aS = (ushort*)(sm + AS_OFF);
  #pragma unroll
  for (int i = 0; i < 16; ++i) {
    float ev = (j < KW) ? e[i] : -3.4e38f;
    float m = ev;
    m = fmaxf(m, __shfl_xor(m, 16)); m = fmaxf(m, __shfl_xor(m, 8));
    m = fmaxf(m, __shfl_xor(m, 4));  m = fmaxf(m, __shfl_xor(m, 2));
    m = fmaxf(m, __shfl_xor(m, 1));
    float ex = (j < KW) ? __expf(ev - m) : 0.f;
    float ssum = ex;
    ssum += __shfl_xor(ssum, 16); ssum += __shfl_xor(ssum, 8);
    ssum += __shfl_xor(ssum, 4);  ssum += __shfl_xor(ssum, 2);
    ssum += __shfl_xor(ssum, 1);
    float a = ex / ssum;
    aS[(i * 8 + g) * 32 + j] = f2bf(a);
    if (j < KW) attn[((bT + t0 + i) * 8 + g) * 31 + j] = a;
  }

  // ---- PV: lane = (tsub=j>>3, dchunk=j&7) ----
  {
    int tsub = j >> 3;
    int d8 = (j & 7) * 8;     // byte offset of 4 bf16 within row-group
    #pragma unroll
    for (int ii = 0; ii < 4; ++ii) {
      int tq = ii * 4 + tsub;
      float o0 = 0.f, o1 = 0.f, o2 = 0.f, o3 = 0.f;
      #pragma unroll
      for (int kp4 = 0; kp4 < 8; ++kp4) {
        uint2 a4 = *(const uint2*)(sm + AS_OFF + (tq * 8 + g) * 64 + kp4 * 8);
        float a0 = bflo(a4.x), a1 = bfhi(a4.x), a2 = bflo(a4.y), a3 = bfhi(a4.y);
        #pragma unroll
        for (int c = 0; c < 4; ++c) {
          float ac = (c == 0) ? a0 : (c == 1) ? a1 : (c == 2) ? a2 : a3;
          int row = tq + kp4 * 4 + c;
          uint2 v4 = *(const uint2*)(sm + VS_OFF + ((row * 512 + g * 64 + d8) ^ ((row & 7) << 4)));
          o0 += ac * bflo(v4.x);
          o1 += ac * bfhi(v4.x);
          o2 += ac * bflo(v4.y);
          o3 += ac * bfhi(v4.y);
        }
      }
      *(float4*)(sm + HS_OFF + tq * 1040 + g * 128 + (j & 7) * 16) = make_float4(o0, o1, o2, o3);
    }
  }
  __syncthreads();   // hS complete; vS/aS dead

  // ---- stage lw -> lwS bf16 [88][264] ----
  ushort* lwS = (ushort*)(sm + LW_OFF);
  for (int idx = tid; idx < 88 * 32; idx += 256) {
    int o = idx >> 5, c8 = idx & 31;
    float4 wa = *(const float4*)(lw + o * 256 + c8 * 8);
    float4 wb = *(const float4*)(lw + o * 256 + c8 * 8 + 4);
    uint4 p;
    p.x = (uint)f2bf(wa.x) | ((uint)f2bf(wa.y) << 16);
    p.y = (uint)f2bf(wa.z) | ((uint)f2bf(wa.w) << 16);
    p.z = (uint)f2bf(wb.x) | ((uint)f2bf(wb.y) << 16);
    p.w = (uint)f2bf(wb.z) | ((uint)f2bf(wb.w) << 16);
    *(uint4*)(&lwS[o * 264 + c8 * 8]) = p;
  }

  // ---- LN (half-wave per t; lane owns 8 contiguous d) ----
  float hn[2][8];
  #pragma unroll
  for (int hf = 0; hf < 2; ++hf) {
    int t = g + hf * 8;
    float4 x0 = *(const float4*)(sm + HS_OFF + t * 1040 + j * 32);
    float4 x1 = *(const float4*)(sm + HS_OFF + t * 1040 + j * 32 + 16);
    float s1 = x0.x + x0.y + x0.z + x0.w + x1.x + x1.y + x1.z + x1.w;
    float s2 = x0.x * x0.x + x0.y * x0.y + x0.z * x0.z + x0.w * x0.w +
               x1.x * x1.x + x1.y * x1.y + x1.z * x1.z + x1.w * x1.w;
    s1 += __shfl_xor(s1, 16); s2 += __shfl_xor(s2, 16);
    s1 += __shfl_xor(s1, 8);  s2 += __shfl_xor(s2, 8);
    s1 += __shfl_xor(s1, 4);  s2 += __shfl_xor(s2, 4);
    s1 += __shfl_xor(s1, 2);  s2 += __shfl_xor(s2, 2);
    s1 += __shfl_xor(s1, 1);  s2 += __shfl_xor(s2, 1);
    float mu = s1 * (1.f / 256.f);
    float var = s2 * (1.f / 256.f) - mu * mu;
    float inv = rsqrtf(var + LN_EPS);
    float4 ga = *(const float4*)(lng + j * 8);
    float4 gb = *(const float4*)(lng + j * 8 + 4);
    float4 ba = *(const float4*)(lnb + j * 8);
    float4 bb = *(const float4*)(lnb + j * 8 + 4);
    hn[hf][0] = (x0.x - mu) * inv * ga.x + ba.x;
    hn[hf][1] = (x0.y - mu) * inv * ga.y + ba.y;
    hn[hf][2] = (x0.z - mu) * inv * ga.z + ba.z;
    hn[hf][3] = (x0.w - mu) * inv * ga.w + ba.w;
    hn[hf][4] = (x1.x - mu) * inv * gb.x + bb.x;
    hn[hf][5] = (x1.y - mu) * inv * gb.y + bb.y;
    hn[hf][6] = (x1.z - mu) * inv * gb.z + bb.z;
    hn[hf][7] = (x1.w - mu) * inv * gb.w + bb.w;
  }
  __syncthreads();   // lwS ready

  // ---- linear + sigmoid ----
  for (int o = 0; o < O_; ++o) {
    uint4 wv = *(const uint4*)(&lwS[o * 264 + j * 8]);
    float w0 = bflo(wv.x), w1 = bfhi(wv.x), w2 = bflo(wv.y), w3 = bfhi(wv.y);
    float w4 = bflo(wv.z), w5 = bfhi(wv.z), w6 = bflo(wv.w), w7 = bfhi(wv.w);
    float acc0 = hn[0][0] * w0 + hn[0][1] * w1 + hn[0][2] * w2 + hn[0][3] * w3 +
                 hn[0][4] * w4 + hn[0][5] * w5 + hn[0][6] * w6 + hn[0][7] * w7;
    float acc1 = hn[1][0] * w0 + hn[1][1] * w1 + hn[1][2] * w2 + hn[1][3] * w3 +
                 hn[1][4] * w4 + hn[1][5] * w5 + hn[1][6] * w6 + hn[1][7] * w7;
    acc0 += __shfl_xor(acc0, 16); acc1 += __shfl_xor(acc1, 16);
    acc0 += __shfl_xor(acc0, 8);  acc1 += __shfl_xor(acc1, 8);
    acc0 += __shfl_xor(acc0, 4);  acc1 += __shfl_xor(acc1, 4);
    acc0 += __shfl_xor(acc0, 2);  acc1 += __shfl_xor(acc1, 2);
    acc0 += __shfl_xor(acc0, 1);  acc1 += __shfl_xor(acc1, 1);
    if (j == 0) {
      float bo = lb[o];
      frame[(bT + t0 + g) * 88 + o] = 1.f / (1.f + __expf(-(acc0 + bo)));
      frame[(bT + t0 + g + 8) * 88 + o] = 1.f / (1.f + __expf(-(acc1 + bo)));
    }
  }
}

extern "C" void kernel_launch(void* const* d_in, const int* in_sizes, int n_in,
                              void* d_out, int out_size, void* d_ws, size_t ws_size,
                              hipStream_t stream) {
  const float* spec = (const float*)d_in[0];
  const float* Wq   = (const float*)d_in[1];
  const float* Wk   = (const float*)d_in[2];
  const float* Wv   = (const float*)d_in[3];
  const float* rel  = (const float*)d_in[4];
  const float* lng  = (const float*)d_in[5];
  const float* lnb  = (const float*)d_in[6];
  const float* lw   = (const float*)d_in[7];
  const float* lb   = (const float*)d_in[8];

  float* out   = (float*)d_out;
  float* frame = out;                              // B*T*O
  float* attn  = out + (long)B_ * T_ * O_;         // B*T*G*KW

  char* ws = (char*)d_ws;
  ushort* W2  = (ushort*)ws;                        // 768*512 bf16
  float*  qb  = (float*)(ws + (1 << 20));           // [16384][256] f32
  ushort* khi = (ushort*)(ws + (1 << 20) + (16 << 20));
  ushort* klo = khi + (long)16384 * 256;
  ushort* vb  = klo + (long)16384 * 256;

  conv_w2<<<768, 256, 0, stream>>>(Wq, Wk, Wv, W2);
  proj_mfma<<<dim3(128, 6), 256, 0, stream>>>(spec, W2, qb, khi, klo, vb);
  attn3<<<dim3(256, 4), 256, 0, stream>>>(qb, khi, klo, vb, rel, lng, lnb, lw, lb, frame, attn);
}

// Round 7
// 369.785 us; speedup vs baseline: 2.6358x; 2.6358x over previous
//
#include <hip/hip_runtime.h>
#include <hip/hip_bf16.h>

typedef unsigned int uint;
typedef unsigned short ushort;

#define B_ 4
#define T_ 4096
#define FIN 229
#define D_ 256
#define O_ 88
#define KW 31
#define G_ 8
#define LN_EPS 1e-5f

typedef __attribute__((ext_vector_type(8))) short short8;
typedef __attribute__((ext_vector_type(4))) float f32x4;

__device__ __forceinline__ ushort f2bf(float x) {
  uint u = __float_as_uint(x);
  uint r = (u + 0x7fffu + ((u >> 16) & 1u)) >> 16;
  return (ushort)r;
}
__device__ __forceinline__ float bflo(uint u) { return __uint_as_float(u << 16); }
__device__ __forceinline__ float bfhi(uint u) { return __uint_as_float(u & 0xffff0000u); }

// ---------- weights -> W2 [768][512] bf16: cols 0-255 hi, 256-511 lo ----------
__global__ __launch_bounds__(256) void conv_w2(const float* __restrict__ Wq,
                                               const float* __restrict__ Wk,
                                               const float* __restrict__ Wv,
                                               ushort* __restrict__ W2) {
  int d3 = blockIdx.x;          // 0..767
  int f = threadIdx.x;          // 0..255
  const float* src = (d3 < 256) ? Wq : (d3 < 512 ? Wk : Wv);
  int dr = d3 & 255;
  float x = (f < FIN) ? src[dr * FIN + f] : 0.f;
  ushort hi = f2bf(x);
  float rem = x - bflo((uint)hi);
  ushort lo = f2bf(rem);
  W2[(long)d3 * 512 + f] = hi;
  W2[(long)d3 * 512 + 256 + f] = lo;
}

// ---------- 3-term MFMA projection ----------
// K slots: seg0 (A hi * W hi), seg1 (A lo * W hi), seg2 (A hi * W lo)
#define KSTEPS 24
__global__ __launch_bounds__(256) void proj_mfma(const float* __restrict__ spec,
                                                 const ushort* __restrict__ W2,
                                                 float* __restrict__ qb,
                                                 float* __restrict__ kb,
                                                 ushort* __restrict__ vb) {
  __shared__ ushort As[128 * 40];
  __shared__ ushort Bs[128 * 40];
  int tid = threadIdx.x;
  int lane = tid & 63, w = tid >> 6;
  int bm = blockIdx.x, bn = blockIdx.y;
  int l15 = lane & 15, kg = lane >> 4;

  int rA = tid >> 1;            // 0..127
  int c0 = (tid & 1) * 16;      // 0 or 16
  const float* srow = spec + (long)(bm * 128 + rA) * FIN;
  const ushort* brow = W2 + (long)(bn * 128 + rA) * 512;

  f32x4 acc[2][8];
  #pragma unroll
  for (int mi = 0; mi < 2; ++mi)
    #pragma unroll
    for (int nf = 0; nf < 8; ++nf)
      acc[mi][nf] = (f32x4){0.f, 0.f, 0.f, 0.f};

  for (int s = 0; s < KSTEPS; ++s) {
    int seg = s >> 3;
    int f0 = (s & 7) * 32;
    int bcol = (seg == 2 ? 256 : 0) + f0;

    float xs[16];
    #pragma unroll
    for (int u = 0; u < 16; ++u) {
      int f = f0 + c0 + u;
      xs[u] = (f < FIN) ? srow[f] : 0.f;
    }
    ushort hv[16];
    if (seg == 1) {
      #pragma unroll
      for (int u = 0; u < 16; ++u) {
        ushort hi = f2bf(xs[u]);
        hv[u] = f2bf(xs[u] - bflo((uint)hi));
      }
    } else {
      #pragma unroll
      for (int u = 0; u < 16; ++u) hv[u] = f2bf(xs[u]);
    }
    uint4 b0 = *(const uint4*)(brow + bcol + c0);
    uint4 b1 = *(const uint4*)(brow + bcol + c0 + 8);

    __syncthreads();
    uint4 ap0, ap1;
    ap0.x = (uint)hv[0] | ((uint)hv[1] << 16);
    ap0.y = (uint)hv[2] | ((uint)hv[3] << 16);
    ap0.z = (uint)hv[4] | ((uint)hv[5] << 16);
    ap0.w = (uint)hv[6] | ((uint)hv[7] << 16);
    ap1.x = (uint)hv[8] | ((uint)hv[9] << 16);
    ap1.y = (uint)hv[10] | ((uint)hv[11] << 16);
    ap1.z = (uint)hv[12] | ((uint)hv[13] << 16);
    ap1.w = (uint)hv[14] | ((uint)hv[15] << 16);
    *(uint4*)(&As[rA * 40 + c0]) = ap0;
    *(uint4*)(&As[rA * 40 + c0 + 8]) = ap1;
    *(uint4*)(&Bs[rA * 40 + c0]) = b0;
    *(uint4*)(&Bs[rA * 40 + c0 + 8]) = b1;
    __syncthreads();

    short8 af[2];
    af[0] = *(const short8*)(&As[(w * 32 + l15) * 40 + kg * 8]);
    af[1] = *(const short8*)(&As[(w * 32 + 16 + l15) * 40 + kg * 8]);
    short8 bfr[8];
    #pragma unroll
    for (int nf = 0; nf < 8; ++nf)
      bfr[nf] = *(const short8*)(&Bs[(nf * 16 + l15) * 40 + kg * 8]);
    #pragma unroll
    for (int mi = 0; mi < 2; ++mi)
      #pragma unroll
      for (int nf = 0; nf < 8; ++nf)
        acc[mi][nf] = __builtin_amdgcn_mfma_f32_16x16x32_bf16(af[mi], bfr[nf], acc[mi][nf], 0, 0, 0);
  }

  #pragma unroll
  for (int mi = 0; mi < 2; ++mi)
    #pragma unroll
    for (int nf = 0; nf < 8; ++nf)
      #pragma unroll
      for (int ic = 0; ic < 4; ++ic) {
        int row = bm * 128 + w * 32 + mi * 16 + kg * 4 + ic;
        int col = bn * 128 + nf * 16 + l15;
        float val = acc[mi][nf][ic];
        if (bn < 2) {
          qb[(long)row * 256 + col] = val;
        } else if (bn < 4) {
          kb[(long)row * 256 + (col - 256)] = val;
        } else {
          vb[(long)row * 256 + (col - 512)] = f2bf(val);
        }
      }
}

// ---------- fused attention + LN + linear ----------
// 8-row t-tiles. LDS layout (bytes):
//   kS @0      [39][260] f32   (40560, pad 40576)
//   vS @40576  [39][256] bf16  swz ((r&7)<<4)  (19968)
//   qS @60544  [8][260]  f32   (8320)
//   aS @68864  [8][8][32] bf16 (4096)
// overlays (after e-loop):  hS @0 [8][260] f32 (8320);  lwS @8320 [88][264] bf16 (46464)
#define TROWS 8
#define KROWS 39
#define KS_OFF 0
#define VS_OFF 40576
#define QS_OFF 60544
#define AS_OFF 68864
#define HS_OFF 0
#define LW_OFF 8320
#define SM_BYTES 72960

__global__ __launch_bounds__(256) void attn4(
    const float* __restrict__ qb, const float* __restrict__ kb,
    const ushort* __restrict__ vb, const float* __restrict__ rel,
    const float* __restrict__ lng, const float* __restrict__ lnb,
    const float* __restrict__ lw, const float* __restrict__ lb,
    float* __restrict__ frame, float* __restrict__ attn) {
  __shared__ alignas(16) char sm[SM_BYTES];

  int tid = threadIdx.x;
  int b = blockIdx.y;
  int t0 = blockIdx.x * TROWS;
  long bT = (long)b * T_;
  int g = tid >> 5;
  int j = tid & 31;

  // ---- stage k (f32), v (bf16 swz), q (f32) ----
  for (int idx = tid; idx < KROWS * 64; idx += 256) {
    int r = idx >> 6, c4 = idx & 63;
    int grow = t0 + r - 15;
    float4 kv = make_float4(0.f, 0.f, 0.f, 0.f);
    if ((unsigned)grow < (unsigned)T_)
      kv = *(const float4*)(kb + (bT + grow) * 256 + c4 * 4);
    *(float4*)(sm + KS_OFF + r * 1040 + c4 * 16) = kv;
  }
  for (int idx = tid; idx < KROWS * 32; idx += 256) {
    int r = idx >> 5, c16 = idx & 31;
    int grow = t0 + r - 15;
    uint4 vv = {0u, 0u, 0u, 0u};
    if ((unsigned)grow < (unsigned)T_)
      vv = *(const uint4*)(vb + (bT + grow) * 256 + c16 * 8);
    *(uint4*)(sm + VS_OFF + ((r * 512 + c16 * 16) ^ ((r & 7) << 4))) = vv;
  }
  for (int idx = tid; idx < TROWS * 64; idx += 256) {
    int r = idx >> 6, c4 = idx & 63;
    float4 qv = *(const float4*)(qb + (bT + t0 + r) * 256 + c4 * 4);
    *(float4*)(sm + QS_OFF + r * 1040 + c4 * 16) = qv;
  }
  // rel into registers: relf[c] = rel[(g*32+c)*31 + j]  (lane j = kp)
  float relf[32];
  #pragma unroll
  for (int c = 0; c < 32; ++c)
    relf[c] = (j < KW) ? rel[(g * 32 + c) * 31 + j] : 0.f;
  __syncthreads();

  // ---- energy + softmax per t (scalar e, no persistent arrays) ----
  ushort* aS = (ushort*)(sm + AS_OFF);
  #pragma unroll 1
  for (int i = 0; i < TROWS; ++i) {
    int row = i + j;
    float ek0 = 0.f, ek1 = 0.f, ek2 = 0.f, ek3 = 0.f;
    float er0 = 0.f, er1 = 0.f, er2 = 0.f, er3 = 0.f;
    #pragma unroll
    for (int c = 0; c < 4; ++c) {
      float4 ka = *(const float4*)(sm + KS_OFF + row * 1040 + g * 128 + c * 32);
      float4 kc = *(const float4*)(sm + KS_OFF + row * 1040 + g * 128 + c * 32 + 16);
      float4 qa = *(const float4*)(sm + QS_OFF + i * 1040 + g * 128 + c * 32);
      float4 qc = *(const float4*)(sm + QS_OFF + i * 1040 + g * 128 + c * 32 + 16);
      ek0 += qa.x * ka.x + qa.y * ka.y;
      ek1 += qa.z * ka.z + qa.w * ka.w;
      ek2 += qc.x * kc.x + qc.y * kc.y;
      ek3 += qc.z * kc.z + qc.w * kc.w;
      er0 += qa.x * relf[c * 8 + 0] + qa.y * relf[c * 8 + 1];
      er1 += qa.z * relf[c * 8 + 2] + qa.w * relf[c * 8 + 3];
      er2 += qc.x * relf[c * 8 + 4] + qc.y * relf[c * 8 + 5];
      er3 += qc.z * relf[c * 8 + 6] + qc.w * relf[c * 8 + 7];
    }
    float e = ((ek0 + ek1) + (ek2 + ek3)) + ((er0 + er1) + (er2 + er3));
    float ev = (j < KW) ? e : -3.4e38f;
    float m = ev;
    m = fmaxf(m, __shfl_xor(m, 16)); m = fmaxf(m, __shfl_xor(m, 8));
    m = fmaxf(m, __shfl_xor(m, 4));  m = fmaxf(m, __shfl_xor(m, 2));
    m = fmaxf(m, __shfl_xor(m, 1));
    float ex = (j < KW) ? __expf(ev - m) : 0.f;
    float ssum = ex;
    ssum += __shfl_xor(ssum, 16); ssum += __shfl_xor(ssum, 8);
    ssum += __shfl_xor(ssum, 4);  ssum += __shfl_xor(ssum, 2);
    ssum += __shfl_xor(ssum, 1);
    float a = ex / ssum;
    aS[(i * 8 + g) * 32 + j] = f2bf(a);
    if (j < KW) attn[((bT + t0 + i) * 8 + g) * 31 + j] = a;
  }
  __syncthreads();   // all kS/qS reads done; hS overlay may be written

  // ---- PV: lane = (tsub=j>>3, dchunk=j&7) ----
  {
    int tsub = j >> 3;
    int d8 = (j & 7) * 8;
    #pragma unroll
    for (int ii = 0; ii < 2; ++ii) {
      int tq = ii * 4 + tsub;
      float o0 = 0.f, o1 = 0.f, o2 = 0.f, o3 = 0.f;
      #pragma unroll
      for (int kp4 = 0; kp4 < 8; ++kp4) {
        uint2 a4 = *(const uint2*)(sm + AS_OFF + (tq * 8 + g) * 64 + kp4 * 8);
        float a0 = bflo(a4.x), a1 = bfhi(a4.x), a2 = bflo(a4.y), a3 = bfhi(a4.y);
        #pragma unroll
        for (int c = 0; c < 4; ++c) {
          float ac = (c == 0) ? a0 : (c == 1) ? a1 : (c == 2) ? a2 : a3;
          int row = tq + kp4 * 4 + c;
          uint2 v4 = *(const uint2*)(sm + VS_OFF + ((row * 512 + g * 64 + d8) ^ ((row & 7) << 4)));
          o0 += ac * bflo(v4.x);
          o1 += ac * bfhi(v4.x);
          o2 += ac * bflo(v4.y);
          o3 += ac * bfhi(v4.y);
        }
      }
      *(float4*)(sm + HS_OFF + tq * 1040 + g * 128 + (j & 7) * 16) = make_float4(o0, o1, o2, o3);
    }
  }
  __syncthreads();   // hS complete; vS/aS dead

  // ---- stage lw -> lwS bf16 [88][264] (over dead kS/vS region) ----
  ushort* lwS = (ushort*)(sm + LW_OFF);
  for (int idx = tid; idx < 88 * 32; idx += 256) {
    int o = idx >> 5, c8 = idx & 31;
    float4 wa = *(const float4*)(lw + o * 256 + c8 * 8);
    float4 wb = *(const float4*)(lw + o * 256 + c8 * 8 + 4);
    uint4 p;
    p.x = (uint)f2bf(wa.x) | ((uint)f2bf(wa.y) << 16);
    p.y = (uint)f2bf(wa.z) | ((uint)f2bf(wa.w) << 16);
    p.z = (uint)f2bf(wb.x) | ((uint)f2bf(wb.y) << 16);
    p.w = (uint)f2bf(wb.z) | ((uint)f2bf(wb.w) << 16);
    *(uint4*)(&lwS[o * 264 + c8 * 8]) = p;
  }

  // ---- LN: halfwave g owns t = g; lane owns 8 contiguous d ----
  float4 x0 = *(const float4*)(sm + HS_OFF + g * 1040 + j * 32);
  float4 x1 = *(const float4*)(sm + HS_OFF + g * 1040 + j * 32 + 16);
  float s1 = x0.x + x0.y + x0.z + x0.w + x1.x + x1.y + x1.z + x1.w;
  float s2 = x0.x * x0.x + x0.y * x0.y + x0.z * x0.z + x0.w * x0.w +
             x1.x * x1.x + x1.y * x1.y + x1.z * x1.z + x1.w * x1.w;
  s1 += __shfl_xor(s1, 16); s2 += __shfl_xor(s2, 16);
  s1 += __shfl_xor(s1, 8);  s2 += __shfl_xor(s2, 8);
  s1 += __shfl_xor(s1, 4);  s2 += __shfl_xor(s2, 4);
  s1 += __shfl_xor(s1, 2);  s2 += __shfl_xor(s2, 2);
  s1 += __shfl_xor(s1, 1);  s2 += __shfl_xor(s2, 1);
  float mu = s1 * (1.f / 256.f);
  float var = s2 * (1.f / 256.f) - mu * mu;
  float inv = rsqrtf(var + LN_EPS);
  float4 ga = *(const float4*)(lng + j * 8);
  float4 gb = *(const float4*)(lng + j * 8 + 4);
  float4 ba = *(const float4*)(lnb + j * 8);
  float4 bb = *(const float4*)(lnb + j * 8 + 4);
  float hn0 = (x0.x - mu) * inv * ga.x + ba.x;
  float hn1 = (x0.y - mu) * inv * ga.y + ba.y;
  float hn2 = (x0.z - mu) * inv * ga.z + ba.z;
  float hn3 = (x0.w - mu) * inv * ga.w + ba.w;
  float hn4 = (x1.x - mu) * inv * gb.x + bb.x;
  float hn5 = (x1.y - mu) * inv * gb.y + bb.y;
  float hn6 = (x1.z - mu) * inv * gb.z + bb.z;
  float hn7 = (x1.w - mu) * inv * gb.w + bb.w;
  __syncthreads();   // lwS ready

  // ---- linear + sigmoid (halfwave g -> t = t0+g) ----
  for (int o = 0; o < O_; ++o) {
    uint4 wv = *(const uint4*)(&lwS[o * 264 + j * 8]);
    float acc0 = hn0 * bflo(wv.x) + hn1 * bfhi(wv.x) + hn2 * bflo(wv.y) + hn3 * bfhi(wv.y) +
                 hn4 * bflo(wv.z) + hn5 * bfhi(wv.z) + hn6 * bflo(wv.w) + hn7 * bfhi(wv.w);
    acc0 += __shfl_xor(acc0, 16);
    acc0 += __shfl_xor(acc0, 8);
    acc0 += __shfl_xor(acc0, 4);
    acc0 += __shfl_xor(acc0, 2);
    acc0 += __shfl_xor(acc0, 1);
    if (j == 0) {
      frame[(bT + t0 + g) * 88 + o] = 1.f / (1.f + __expf(-(acc0 + lb[o])));
    }
  }
}

extern "C" void kernel_launch(void* const* d_in, const int* in_sizes, int n_in,
                              void* d_out, int out_size, void* d_ws, size_t ws_size,
                              hipStream_t stream) {
  const float* spec = (const float*)d_in[0];
  const float* Wq   = (const float*)d_in[1];
  const float* Wk   = (const float*)d_in[2];
  const float* Wv   = (const float*)d_in[3];
  const float* rel  = (const float*)d_in[4];
  const float* lng  = (const float*)d_in[5];
  const float* lnb  = (const float*)d_in[6];
  const float* lw   = (const float*)d_in[7];
  const float* lb   = (const float*)d_in[8];

  float* out   = (float*)d_out;
  float* frame = out;                              // B*T*O
  float* attn  = out + (long)B_ * T_ * O_;         // B*T*G*KW

  char* ws = (char*)d_ws;
  ushort* W2  = (ushort*)ws;                        // 768*512 bf16
  float*  qb  = (float*)(ws + (1 << 20));           // [16384][256] f32
  float*  kb  = (float*)(ws + (1 << 20) + (16 << 20));  // [16384][256] f32
  ushort* vb  = (ushort*)(ws + (1 << 20) + (32 << 20)); // [16384][256] bf16

  conv_w2<<<768, 256, 0, stream>>>(Wq, Wk, Wv, W2);
  proj_mfma<<<dim3(128, 6), 256, 0, stream>>>(spec, W2, qb, kb, vb);
  attn4<<<dim3(512, 4), 256, 0, stream>>>(qb, kb, vb, rel, lng, lnb, lw, lb, frame, attn);
}

// Round 10
// 214.182 us; speedup vs baseline: 4.5506x; 1.7265x over previous
//
#include <hip/hip_runtime.h>
#include <hip/hip_bf16.h>

typedef unsigned int uint;
typedef unsigned short ushort;

#define B_ 4
#define T_ 4096
#define FIN 229
#define D_ 256
#define O_ 88
#define KW 31
#define G_ 8
#define LN_EPS 1e-5f
#define SBW 464
#define W2W 512

typedef __attribute__((ext_vector_type(8))) short short8;
typedef __attribute__((ext_vector_type(4))) float f32x4;

__device__ __forceinline__ ushort f2bf(float x) {
  uint u = __float_as_uint(x);
  uint r = (u + 0x7fffu + ((u >> 16) & 1u)) >> 16;
  return (ushort)r;
}
__device__ __forceinline__ float bflo(uint u) { return __uint_as_float(u << 16); }
__device__ __forceinline__ float bfhi(uint u) { return __uint_as_float(u & 0xffff0000u); }

// ---------- spec f32 -> specB [16384][464] bf16 (hi 0..231 | lo 232..463) ----------
__global__ __launch_bounds__(256) void conv_spec(const float* __restrict__ spec,
                                                 ushort* __restrict__ specB) {
  int row = blockIdx.x;
  int f = threadIdx.x;
  if (f >= 232) return;
  float x = (f < FIN) ? spec[(long)row * FIN + f] : 0.f;
  ushort hi = f2bf(x);
  ushort lo = f2bf(x - bflo((uint)hi));
  specB[(long)row * SBW + f] = hi;
  specB[(long)row * SBW + 232 + f] = lo;
}

// ---------- weights -> W2 [768][512] bf16: cols 0-255 hi, 256-511 lo ----------
__global__ __launch_bounds__(256) void conv_w2(const float* __restrict__ Wq,
                                               const float* __restrict__ Wk,
                                               const float* __restrict__ Wv,
                                               ushort* __restrict__ W2) {
  int d3 = blockIdx.x;
  int f = threadIdx.x;
  const float* src = (d3 < 256) ? Wq : (d3 < 512 ? Wk : Wv);
  int dr = d3 & 255;
  float x = (f < FIN) ? src[dr * FIN + f] : 0.f;
  ushort hi = f2bf(x);
  ushort lo = f2bf(x - bflo((uint)hi));
  W2[(long)d3 * W2W + f] = hi;
  W2[(long)d3 * W2W + 256 + f] = lo;
}

// ---------- lw f32 [88][256] -> lwB bf16 [96][256] (rows 88-95 zero) ----------
__global__ __launch_bounds__(256) void conv_lw(const float* __restrict__ lw,
                                               ushort* __restrict__ lwB) {
  int o = blockIdx.x;
  int d = threadIdx.x;
  lwB[o * 256 + d] = (o < O_) ? f2bf(lw[o * 256 + d]) : (ushort)0;
}

// ---------- 3-term MFMA projection: [16384][768] = specB(3seg) @ W2(3seg)^T ----------
#define KSTEPS 24
__global__ __launch_bounds__(256) void proj_mfma(const ushort* __restrict__ specB,
                                                 const ushort* __restrict__ W2,
                                                 float* __restrict__ qb,
                                                 float* __restrict__ kb,
                                                 ushort* __restrict__ vb) {
  __shared__ ushort As[128 * 32];
  __shared__ ushort Bs[128 * 32];
  int tid = threadIdx.x;
  int lane = tid & 63, w = tid >> 6;
  int bm = blockIdx.x, bn = blockIdx.y;
  int l15 = lane & 15, kg = lane >> 4;
  int rS = tid >> 1, cS = (tid & 1) * 16;

  const ushort* arow = specB + (long)(bm * 128 + rS) * SBW;
  const ushort* brow = W2 + (long)(bn * 128 + rS) * W2W;

  f32x4 acc[2][8];
  #pragma unroll
  for (int mi = 0; mi < 2; ++mi)
    #pragma unroll
    for (int nf = 0; nf < 8; ++nf)
      acc[mi][nf] = (f32x4){0.f, 0.f, 0.f, 0.f};

  for (int s = 0; s < KSTEPS; ++s) {
    int seg = s >> 3;
    int f0 = (s & 7) * 32;
    int acol = (seg == 1 ? 232 : 0) + f0;   // A: hi, lo, hi
    int bcol = (seg == 2 ? 256 : 0) + f0;   // B: hi, hi, lo

    // full 16 ushorts per thread: TWO uint4 loads (8 ushorts each)
    uint4 a0 = *(const uint4*)(arow + acol + cS);
    uint4 a1 = *(const uint4*)(arow + acol + cS + 8);
    uint4 b0 = *(const uint4*)(brow + bcol + cS);
    uint4 b1 = *(const uint4*)(brow + bcol + cS + 8);
    __syncthreads();
    *(uint4*)(&As[rS * 32 + cS]) = a0;
    *(uint4*)(&As[rS * 32 + cS + 8]) = a1;
    *(uint4*)(&Bs[rS * 32 + cS]) = b0;
    *(uint4*)(&Bs[rS * 32 + cS + 8]) = b1;
    __syncthreads();

    short8 af[2];
    af[0] = *(const short8*)(&As[(w * 32 + l15) * 32 + kg * 8]);
    af[1] = *(const short8*)(&As[(w * 32 + 16 + l15) * 32 + kg * 8]);
    short8 bfr[8];
    #pragma unroll
    for (int nf = 0; nf < 8; ++nf)
      bfr[nf] = *(const short8*)(&Bs[(nf * 16 + l15) * 32 + kg * 8]);
    #pragma unroll
    for (int mi = 0; mi < 2; ++mi)
      #pragma unroll
      for (int nf = 0; nf < 8; ++nf)
        acc[mi][nf] = __builtin_amdgcn_mfma_f32_16x16x32_bf16(af[mi], bfr[nf], acc[mi][nf], 0, 0, 0);
  }

  #pragma unroll
  for (int mi = 0; mi < 2; ++mi)
    #pragma unroll
    for (int nf = 0; nf < 8; ++nf)
      #pragma unroll
      for (int ic = 0; ic < 4; ++ic) {
        int row = bm * 128 + w * 32 + mi * 16 + kg * 4 + ic;
        int col = bn * 128 + nf * 16 + l15;
        float val = acc[mi][nf][ic];
        if (bn < 2) {
          qb[(long)row * 256 + col] = val;
        } else if (bn < 4) {
          kb[(long)row * 256 + (col - 256)] = val;
        } else {
          vb[(long)row * 256 + (col - 512)] = f2bf(val);
        }
      }
}

// ---------- fused attention + LN, writes h bf16 ----------
#define TROWS 8
#define KROWS 39
#define KS_OFF 0
#define VS_OFF 40576
#define QS_OFF 60544
#define AS_OFF 68864
#define HS_OFF 0
#define SM_BYTES 72960

__global__ __launch_bounds__(256) void attn4(
    const float* __restrict__ qb, const float* __restrict__ kb,
    const ushort* __restrict__ vb, const float* __restrict__ rel,
    const float* __restrict__ lng, const float* __restrict__ lnb,
    ushort* __restrict__ hB, float* __restrict__ attn) {
  __shared__ alignas(16) char sm[SM_BYTES];

  int tid = threadIdx.x;
  int b = blockIdx.y;
  int t0 = blockIdx.x * TROWS;
  long bT = (long)b * T_;
  int g = tid >> 5;
  int j = tid & 31;

  for (int idx = tid; idx < KROWS * 64; idx += 256) {
    int r = idx >> 6, c4 = idx & 63;
    int grow = t0 + r - 15;
    float4 kv = make_float4(0.f, 0.f, 0.f, 0.f);
    if ((unsigned)grow < (unsigned)T_)
      kv = *(const float4*)(kb + (bT + grow) * 256 + c4 * 4);
    *(float4*)(sm + KS_OFF + r * 1040 + c4 * 16) = kv;
  }
  for (int idx = tid; idx < KROWS * 32; idx += 256) {
    int r = idx >> 5, c16 = idx & 31;
    int grow = t0 + r - 15;
    uint4 vv = {0u, 0u, 0u, 0u};
    if ((unsigned)grow < (unsigned)T_)
      vv = *(const uint4*)(vb + (bT + grow) * 256 + c16 * 8);
    *(uint4*)(sm + VS_OFF + ((r * 512 + c16 * 16) ^ ((r & 7) << 4))) = vv;
  }
  for (int idx = tid; idx < TROWS * 64; idx += 256) {
    int r = idx >> 6, c4 = idx & 63;
    float4 qv = *(const float4*)(qb + (bT + t0 + r) * 256 + c4 * 4);
    *(float4*)(sm + QS_OFF + r * 1040 + c4 * 16) = qv;
  }
  float relf[32];
  #pragma unroll
  for (int c = 0; c < 32; ++c)
    relf[c] = (j < KW) ? rel[(g * 32 + c) * 31 + j] : 0.f;
  __syncthreads();

  // ---- energy + softmax per t ----
  ushort* aS = (ushort*)(sm + AS_OFF);
  #pragma unroll 1
  for (int i = 0; i < TROWS; ++i) {
    int row = i + j;
    float ek0 = 0.f, ek1 = 0.f, ek2 = 0.f, ek3 = 0.f;
    float er0 = 0.f, er1 = 0.f, er2 = 0.f, er3 = 0.f;
    #pragma unroll
    for (int c = 0; c < 4; ++c) {
      float4 ka = *(const float4*)(sm + KS_OFF + row * 1040 + g * 128 + c * 32);
      float4 kc = *(const float4*)(sm + KS_OFF + row * 1040 + g * 128 + c * 32 + 16);
      float4 qa = *(const float4*)(sm + QS_OFF + i * 1040 + g * 128 + c * 32);
      float4 qc = *(const float4*)(sm + QS_OFF + i * 1040 + g * 128 + c * 32 + 16);
      ek0 += qa.x * ka.x + qa.y * ka.y;
      ek1 += qa.z * ka.z + qa.w * ka.w;
      ek2 += qc.x * kc.x + qc.y * kc.y;
      ek3 += qc.z * kc.z + qc.w * kc.w;
      er0 += qa.x * relf[c * 8 + 0] + qa.y * relf[c * 8 + 1];
      er1 += qa.z * relf[c * 8 + 2] + qa.w * relf[c * 8 + 3];
      er2 += qc.x * relf[c * 8 + 4] + qc.y * relf[c * 8 + 5];
      er3 += qc.z * relf[c * 8 + 6] + qc.w * relf[c * 8 + 7];
    }
    float e = ((ek0 + ek1) + (ek2 + ek3)) + ((er0 + er1) + (er2 + er3));
    float ev = (j < KW) ? e : -3.4e38f;
    float m = ev;
    m = fmaxf(m, __shfl_xor(m, 16)); m = fmaxf(m, __shfl_xor(m, 8));
    m = fmaxf(m, __shfl_xor(m, 4));  m = fmaxf(m, __shfl_xor(m, 2));
    m = fmaxf(m, __shfl_xor(m, 1));
    float ex = (j < KW) ? __expf(ev - m) : 0.f;
    float ssum = ex;
    ssum += __shfl_xor(ssum, 16); ssum += __shfl_xor(ssum, 8);
    ssum += __shfl_xor(ssum, 4);  ssum += __shfl_xor(ssum, 2);
    ssum += __shfl_xor(ssum, 1);
    float a = ex / ssum;
    aS[(i * 8 + g) * 32 + j] = f2bf(a);
    if (j < KW) attn[((bT + t0 + i) * 8 + g) * 31 + j] = a;
  }
  __syncthreads();

  // ---- PV ----
  {
    int tsub = j >> 3;
    int d8 = (j & 7) * 8;
    #pragma unroll
    for (int ii = 0; ii < 2; ++ii) {
      int tq = ii * 4 + tsub;
      float o0 = 0.f, o1 = 0.f, o2 = 0.f, o3 = 0.f;
      #pragma unroll
      for (int kp4 = 0; kp4 < 8; ++kp4) {
        uint2 a4 = *(const uint2*)(sm + AS_OFF + (tq * 8 + g) * 64 + kp4 * 8);
        float a0 = bflo(a4.x), a1 = bfhi(a4.x), a2 = bflo(a4.y), a3 = bfhi(a4.y);
        #pragma unroll
        for (int c = 0; c < 4; ++c) {
          float ac = (c == 0) ? a0 : (c == 1) ? a1 : (c == 2) ? a2 : a3;
          int row = tq + kp4 * 4 + c;
          uint2 v4 = *(const uint2*)(sm + VS_OFF + ((row * 512 + g * 64 + d8) ^ ((row & 7) << 4)));
          o0 += ac * bflo(v4.x);
          o1 += ac * bfhi(v4.x);
          o2 += ac * bflo(v4.y);
          o3 += ac * bfhi(v4.y);
        }
      }
      *(float4*)(sm + HS_OFF + tq * 1040 + g * 128 + (j & 7) * 16) = make_float4(o0, o1, o2, o3);
    }
  }
  __syncthreads();

  // ---- LN: halfwave g owns t = t0+g; lane owns 8 contiguous d; write h bf16 ----
  float4 x0 = *(const float4*)(sm + HS_OFF + g * 1040 + j * 32);
  float4 x1 = *(const float4*)(sm + HS_OFF + g * 1040 + j * 32 + 16);
  float s1 = x0.x + x0.y + x0.z + x0.w + x1.x + x1.y + x1.z + x1.w;
  float s2 = x0.x * x0.x + x0.y * x0.y + x0.z * x0.z + x0.w * x0.w +
             x1.x * x1.x + x1.y * x1.y + x1.z * x1.z + x1.w * x1.w;
  s1 += __shfl_xor(s1, 16); s2 += __shfl_xor(s2, 16);
  s1 += __shfl_xor(s1, 8);  s2 += __shfl_xor(s2, 8);
  s1 += __shfl_xor(s1, 4);  s2 += __shfl_xor(s2, 4);
  s1 += __shfl_xor(s1, 2);  s2 += __shfl_xor(s2, 2);
  s1 += __shfl_xor(s1, 1);  s2 += __shfl_xor(s2, 1);
  float mu = s1 * (1.f / 256.f);
  float var = s2 * (1.f / 256.f) - mu * mu;
  float inv = rsqrtf(var + LN_EPS);
  float4 ga = *(const float4*)(lng + j * 8);
  float4 gb = *(const float4*)(lng + j * 8 + 4);
  float4 ba = *(const float4*)(lnb + j * 8);
  float4 bb = *(const float4*)(lnb + j * 8 + 4);
  uint4 hp;
  hp.x = (uint)f2bf((x0.x - mu) * inv * ga.x + ba.x) |
         ((uint)f2bf((x0.y - mu) * inv * ga.y + ba.y) << 16);
  hp.y = (uint)f2bf((x0.z - mu) * inv * ga.z + ba.z) |
         ((uint)f2bf((x0.w - mu) * inv * ga.w + ba.w) << 16);
  hp.z = (uint)f2bf((x1.x - mu) * inv * gb.x + bb.x) |
         ((uint)f2bf((x1.y - mu) * inv * gb.y + bb.y) << 16);
  hp.w = (uint)f2bf((x1.z - mu) * inv * gb.z + bb.z) |
         ((uint)f2bf((x1.w - mu) * inv * gb.w + bb.w) << 16);
  *(uint4*)(hB + (bT + t0 + g) * 256 + j * 8) = hp;
}

// ---------- final linear + sigmoid via MFMA: frame[16384][88] ----------
__global__ __launch_bounds__(256) void lin_mfma(const ushort* __restrict__ hB,
                                                const ushort* __restrict__ lwB,
                                                const float* __restrict__ lb,
                                                float* __restrict__ frame) {
  __shared__ ushort As[64 * 32];     // 4 KB
  __shared__ ushort Bs[96 * 264];    // 49.5 KB, 528B rows (16B aligned)
  int tid = threadIdx.x;
  int lane = tid & 63, w = tid >> 6;
  int blk = blockIdx.x;
  int l15 = lane & 15, kg = lane >> 4;

  for (int idx = tid; idx < 96 * 32; idx += 256) {
    int o = idx >> 5, c8 = idx & 31;
    uint4 bv = *(const uint4*)(lwB + o * 256 + c8 * 8);
    *(uint4*)(&Bs[o * 264 + c8 * 8]) = bv;
  }

  f32x4 acc[6];
  #pragma unroll
  for (int nf = 0; nf < 6; ++nf) acc[nf] = (f32x4){0.f, 0.f, 0.f, 0.f};

  for (int s = 0; s < 8; ++s) {
    uint4 a0 = {0u, 0u, 0u, 0u}, a1 = {0u, 0u, 0u, 0u};
    if (tid < 128) {
      const ushort* hp = hB + (long)(blk * 64 + (tid >> 1)) * 256 + s * 32 + (tid & 1) * 16;
      a0 = *(const uint4*)(hp);
      a1 = *(const uint4*)(hp + 8);
    }
    __syncthreads();
    if (tid < 128) {
      *(uint4*)(&As[(tid >> 1) * 32 + (tid & 1) * 16]) = a0;
      *(uint4*)(&As[(tid >> 1) * 32 + (tid & 1) * 16 + 8]) = a1;
    }
    __syncthreads();

    short8 af = *(const short8*)(&As[(w * 16 + l15) * 32 + kg * 8]);
    #pragma unroll
    for (int nf = 0; nf < 6; ++nf) {
      short8 bf = *(const short8*)(&Bs[(nf * 16 + l15) * 264 + s * 32 + kg * 8]);
      acc[nf] = __builtin_amdgcn_mfma_f32_16x16x32_bf16(af, bf, acc[nf], 0, 0, 0);
    }
  }

  #pragma unroll
  for (int nf = 0; nf < 6; ++nf) {
    int col = nf * 16 + l15;
    if (col < O_) {
      float bo = lb[col];
      #pragma unroll
      for (int ic = 0; ic < 4; ++ic) {
        int row = blk * 64 + w * 16 + kg * 4 + ic;
        float z = acc[nf][ic] + bo;
        frame[(long)row * O_ + col] = 1.f / (1.f + __expf(-z));
      }
    }
  }
}

extern "C" void kernel_launch(void* const* d_in, const int* in_sizes, int n_in,
                              void* d_out, int out_size, void* d_ws, size_t ws_size,
                              hipStream_t stream) {
  const float* spec = (const float*)d_in[0];
  const float* Wq   = (const float*)d_in[1];
  const float* Wk   = (const float*)d_in[2];
  const float* Wv   = (const float*)d_in[3];
  const float* rel  = (const float*)d_in[4];
  const float* lng  = (const float*)d_in[5];
  const float* lnb  = (const float*)d_in[6];
  const float* lw   = (const float*)d_in[7];
  const float* lb   = (const float*)d_in[8];

  float* out   = (float*)d_out;
  float* frame = out;
  float* attn  = out + (long)B_ * T_ * O_;

  char* ws = (char*)d_ws;
  float*  qb    = (float*)ws;                                // 16 MB
  float*  kb    = (float*)(ws + (16u << 20));                // 16 MB
  ushort* vb    = (ushort*)(ws + (32u << 20));               // 8 MB
  ushort* specB = (ushort*)(ws + (40u << 20));               // 15,204,352 B
  ushort* W2    = (ushort*)(ws + (40u << 20) + 15204352u);   // 786,432 B (absorbs specB tail over-read)
  ushort* lwB   = (ushort*)(ws + (40u << 20) + 15204352u + 786432u);  // 48 KB
  ushort* hB    = specB;                                     // overlay (specB dead after proj)

  conv_spec<<<16384, 256, 0, stream>>>(spec, specB);
  conv_w2<<<768, 256, 0, stream>>>(Wq, Wk, Wv, W2);
  conv_lw<<<96, 256, 0, stream>>>(lw, lwB);
  proj_mfma<<<dim3(128, 6), 256, 0, stream>>>(specB, W2, qb, kb, vb);
  attn4<<<dim3(512, 4), 256, 0, stream>>>(qb, kb, vb, rel, lng, lnb, hB, attn);
  lin_mfma<<<256, 256, 0, stream>>>(hB, lwB, lb, frame);
}

// Round 11
// 193.437 us; speedup vs baseline: 5.0387x; 1.1072x over previous
//
#include <hip/hip_runtime.h>
#include <hip/hip_bf16.h>

typedef unsigned int uint;
typedef unsigned short ushort;

#define B_ 4
#define T_ 4096
#define FIN 229
#define D_ 256
#define O_ 88
#define KW 31
#define G_ 8
#define LN_EPS 1e-5f
#define SBW 464
#define W2W 512

typedef __attribute__((ext_vector_type(8))) short short8;
typedef __attribute__((ext_vector_type(4))) float f32x4;

__device__ __forceinline__ ushort f2bf(float x) {
  uint u = __float_as_uint(x);
  uint r = (u + 0x7fffu + ((u >> 16) & 1u)) >> 16;
  return (ushort)r;
}
__device__ __forceinline__ float bflo(uint u) { return __uint_as_float(u << 16); }
__device__ __forceinline__ float bfhi(uint u) { return __uint_as_float(u & 0xffff0000u); }

// ---------- spec f32 -> specB [16384][464] bf16 (hi 0..231 | lo 232..463) ----------
// 8 rows/block, 29 active lanes of each 32-lane group, uint4 stores
__global__ __launch_bounds__(256) void conv_spec(const float* __restrict__ spec,
                                                 ushort* __restrict__ specB) {
  int tid = threadIdx.x;
  int r = tid >> 5, c = tid & 31;
  if (c >= 29) return;
  long row = (long)blockIdx.x * 8 + r;
  const float* sp = spec + row * FIN + c * 8;
  float x[8];
  #pragma unroll
  for (int u = 0; u < 8; ++u) {
    int f = c * 8 + u;
    x[u] = (f < FIN) ? sp[u] : 0.f;
  }
  ushort hi[8], lo[8];
  #pragma unroll
  for (int u = 0; u < 8; ++u) {
    hi[u] = f2bf(x[u]);
    lo[u] = f2bf(x[u] - bflo((uint)hi[u]));
  }
  uint4 hp, lp;
  hp.x = (uint)hi[0] | ((uint)hi[1] << 16);
  hp.y = (uint)hi[2] | ((uint)hi[3] << 16);
  hp.z = (uint)hi[4] | ((uint)hi[5] << 16);
  hp.w = (uint)hi[6] | ((uint)hi[7] << 16);
  lp.x = (uint)lo[0] | ((uint)lo[1] << 16);
  lp.y = (uint)lo[2] | ((uint)lo[3] << 16);
  lp.z = (uint)lo[4] | ((uint)lo[5] << 16);
  lp.w = (uint)lo[6] | ((uint)lo[7] << 16);
  *(uint4*)(specB + row * SBW + c * 8) = hp;
  *(uint4*)(specB + row * SBW + 232 + c * 8) = lp;
}

// ---------- weights -> W2 [768][512] bf16: cols 0-255 hi, 256-511 lo ----------
__global__ __launch_bounds__(256) void conv_w2(const float* __restrict__ Wq,
                                               const float* __restrict__ Wk,
                                               const float* __restrict__ Wv,
                                               ushort* __restrict__ W2) {
  int d3 = blockIdx.x;
  int f = threadIdx.x;
  const float* src = (d3 < 256) ? Wq : (d3 < 512 ? Wk : Wv);
  int dr = d3 & 255;
  float x = (f < FIN) ? src[dr * FIN + f] : 0.f;
  ushort hi = f2bf(x);
  ushort lo = f2bf(x - bflo((uint)hi));
  W2[(long)d3 * W2W + f] = hi;
  W2[(long)d3 * W2W + 256 + f] = lo;
}

// ---------- lw f32 [88][256] -> lwB bf16 [96][256] (rows 88-95 zero) ----------
__global__ __launch_bounds__(256) void conv_lw(const float* __restrict__ lw,
                                               ushort* __restrict__ lwB) {
  int o = blockIdx.x;
  int d = threadIdx.x;
  lwB[o * 256 + d] = (o < O_) ? f2bf(lw[o * 256 + d]) : (ushort)0;
}

// ---------- 3-term MFMA projection: [16384][768] = specB(3seg) @ W2(3seg)^T ----------
#define KSTEPS 24
__global__ __launch_bounds__(256) void proj_mfma(const ushort* __restrict__ specB,
                                                 const ushort* __restrict__ W2,
                                                 float* __restrict__ qb,
                                                 float* __restrict__ kb,
                                                 ushort* __restrict__ vb) {
  __shared__ ushort As[128 * 40];   // stride 40 (+8 pad): 2-way frag reads
  __shared__ ushort Bs[128 * 40];
  int tid = threadIdx.x;
  int lane = tid & 63, w = tid >> 6;
  int bm = blockIdx.x, bn = blockIdx.y;
  int l15 = lane & 15, kg = lane >> 4;
  int rS = tid >> 1, cS = (tid & 1) * 16;

  const ushort* arow = specB + (long)(bm * 128 + rS) * SBW;
  const ushort* brow = W2 + (long)(bn * 128 + rS) * W2W;

  f32x4 acc[2][8];
  #pragma unroll
  for (int mi = 0; mi < 2; ++mi)
    #pragma unroll
    for (int nf = 0; nf < 8; ++nf)
      acc[mi][nf] = (f32x4){0.f, 0.f, 0.f, 0.f};

  // prefetch step 0
  uint4 a0, a1, b0, b1;
  {
    a0 = *(const uint4*)(arow + cS);
    a1 = *(const uint4*)(arow + cS + 8);
    b0 = *(const uint4*)(brow + cS);
    b1 = *(const uint4*)(brow + cS + 8);
  }

  for (int s = 0; s < KSTEPS; ++s) {
    __syncthreads();
    *(uint4*)(&As[rS * 40 + cS]) = a0;
    *(uint4*)(&As[rS * 40 + cS + 8]) = a1;
    *(uint4*)(&Bs[rS * 40 + cS]) = b0;
    *(uint4*)(&Bs[rS * 40 + cS + 8]) = b1;
    __syncthreads();

    if (s + 1 < KSTEPS) {   // prefetch next step: latency hides under MFMAs
      int sn = s + 1;
      int seg = sn >> 3;
      int f0 = (sn & 7) * 32;
      int acol = (seg == 1 ? 232 : 0) + f0;
      int bcol = (seg == 2 ? 256 : 0) + f0;
      a0 = *(const uint4*)(arow + acol + cS);
      a1 = *(const uint4*)(arow + acol + cS + 8);
      b0 = *(const uint4*)(brow + bcol + cS);
      b1 = *(const uint4*)(brow + bcol + cS + 8);
    }

    short8 af[2];
    af[0] = *(const short8*)(&As[(w * 32 + l15) * 40 + kg * 8]);
    af[1] = *(const short8*)(&As[(w * 32 + 16 + l15) * 40 + kg * 8]);
    short8 bfr[8];
    #pragma unroll
    for (int nf = 0; nf < 8; ++nf)
      bfr[nf] = *(const short8*)(&Bs[(nf * 16 + l15) * 40 + kg * 8]);
    #pragma unroll
    for (int mi = 0; mi < 2; ++mi)
      #pragma unroll
      for (int nf = 0; nf < 8; ++nf)
        acc[mi][nf] = __builtin_amdgcn_mfma_f32_16x16x32_bf16(af[mi], bfr[nf], acc[mi][nf], 0, 0, 0);
  }

  #pragma unroll
  for (int mi = 0; mi < 2; ++mi)
    #pragma unroll
    for (int nf = 0; nf < 8; ++nf)
      #pragma unroll
      for (int ic = 0; ic < 4; ++ic) {
        int row = bm * 128 + w * 32 + mi * 16 + kg * 4 + ic;
        int col = bn * 128 + nf * 16 + l15;
        float val = acc[mi][nf][ic];
        if (bn < 2) {
          qb[(long)row * 256 + col] = val;
        } else if (bn < 4) {
          kb[(long)row * 256 + (col - 256)] = val;
        } else {
          vb[(long)row * 256 + (col - 512)] = f2bf(val);
        }
      }
}

// ---------- fused attention + LN, writes h bf16 ----------
// 16-row t-tiles, 512 threads (16 half-waves). LDS (bytes):
//   kS @0      [47][260] f32  (48880 -> pad 48896)
//   vS @48896  [47][256] bf16 swz ((r&7)<<4)  (24064)
//   qS @72960  [16][260] f32  (16640)
//   aS @89600  [16][8][32] bf16 (8192)
// overlay after energy: hS @0 [16][260] f32 (16640)
#define TROWS 16
#define KROWS 47
#define KS_OFF 0
#define VS_OFF 48896
#define QS_OFF 72960
#define AS_OFF 89600
#define HS_OFF 0
#define SM_BYTES 97792

__global__ __launch_bounds__(512) void attn4(
    const float* __restrict__ qb, const float* __restrict__ kb,
    const ushort* __restrict__ vb, const float* __restrict__ rel,
    const float* __restrict__ lng, const float* __restrict__ lnb,
    ushort* __restrict__ hB, float* __restrict__ attn) {
  __shared__ alignas(16) char sm[SM_BYTES];

  int tid = threadIdx.x;
  int b = blockIdx.y;
  int t0 = blockIdx.x * TROWS;
  long bT = (long)b * T_;
  int h = tid >> 5;          // half-wave 0..15
  int j = tid & 31;
  int g = h & 7;             // group
  int ibase = (h >> 3) * 8;  // t-rows 0..7 or 8..15

  for (int idx = tid; idx < KROWS * 64; idx += 512) {
    int r = idx >> 6, c4 = idx & 63;
    int grow = t0 + r - 15;
    float4 kv = make_float4(0.f, 0.f, 0.f, 0.f);
    if ((unsigned)grow < (unsigned)T_)
      kv = *(const float4*)(kb + (bT + grow) * 256 + c4 * 4);
    *(float4*)(sm + KS_OFF + r * 1040 + c4 * 16) = kv;
  }
  for (int idx = tid; idx < KROWS * 32; idx += 512) {
    int r = idx >> 5, c16 = idx & 31;
    int grow = t0 + r - 15;
    uint4 vv = {0u, 0u, 0u, 0u};
    if ((unsigned)grow < (unsigned)T_)
      vv = *(const uint4*)(vb + (bT + grow) * 256 + c16 * 8);
    *(uint4*)(sm + VS_OFF + ((r * 512 + c16 * 16) ^ ((r & 7) << 4))) = vv;
  }
  for (int idx = tid; idx < TROWS * 64; idx += 512) {
    int r = idx >> 6, c4 = idx & 63;
    float4 qv = *(const float4*)(qb + (bT + t0 + r) * 256 + c4 * 4);
    *(float4*)(sm + QS_OFF + r * 1040 + c4 * 16) = qv;
  }
  float relf[32];
  #pragma unroll
  for (int c = 0; c < 32; ++c)
    relf[c] = (j < KW) ? rel[(g * 32 + c) * 31 + j] : 0.f;
  __syncthreads();

  // ---- energy + softmax: half-wave h does rows ibase..ibase+7 of group g ----
  ushort* aS = (ushort*)(sm + AS_OFF);
  #pragma unroll 1
  for (int ii = 0; ii < 8; ++ii) {
    int i = ibase + ii;
    int row = i + j;
    float ek0 = 0.f, ek1 = 0.f, ek2 = 0.f, ek3 = 0.f;
    float er0 = 0.f, er1 = 0.f, er2 = 0.f, er3 = 0.f;
    #pragma unroll
    for (int c = 0; c < 4; ++c) {
      float4 ka = *(const float4*)(sm + KS_OFF + row * 1040 + g * 128 + c * 32);
      float4 kc = *(const float4*)(sm + KS_OFF + row * 1040 + g * 128 + c * 32 + 16);
      float4 qa = *(const float4*)(sm + QS_OFF + i * 1040 + g * 128 + c * 32);
      float4 qc = *(const float4*)(sm + QS_OFF + i * 1040 + g * 128 + c * 32 + 16);
      ek0 += qa.x * ka.x + qa.y * ka.y;
      ek1 += qa.z * ka.z + qa.w * ka.w;
      ek2 += qc.x * kc.x + qc.y * kc.y;
      ek3 += qc.z * kc.z + qc.w * kc.w;
      er0 += qa.x * relf[c * 8 + 0] + qa.y * relf[c * 8 + 1];
      er1 += qa.z * relf[c * 8 + 2] + qa.w * relf[c * 8 + 3];
      er2 += qc.x * relf[c * 8 + 4] + qc.y * relf[c * 8 + 5];
      er3 += qc.z * relf[c * 8 + 6] + qc.w * relf[c * 8 + 7];
    }
    float e = ((ek0 + ek1) + (ek2 + ek3)) + ((er0 + er1) + (er2 + er3));
    float ev = (j < KW) ? e : -3.4e38f;
    float m = ev;
    m = fmaxf(m, __shfl_xor(m, 16)); m = fmaxf(m, __shfl_xor(m, 8));
    m = fmaxf(m, __shfl_xor(m, 4));  m = fmaxf(m, __shfl_xor(m, 2));
    m = fmaxf(m, __shfl_xor(m, 1));
    float ex = (j < KW) ? __expf(ev - m) : 0.f;
    float ssum = ex;
    ssum += __shfl_xor(ssum, 16); ssum += __shfl_xor(ssum, 8);
    ssum += __shfl_xor(ssum, 4);  ssum += __shfl_xor(ssum, 2);
    ssum += __shfl_xor(ssum, 1);
    float a = ex / ssum;
    aS[(i * 8 + g) * 32 + j] = f2bf(a);
    if (j < KW) attn[((bT + t0 + i) * 8 + g) * 31 + j] = a;
  }
  __syncthreads();   // kS/qS dead; hS overlay may be written

  // ---- PV: half-wave h covers tq = (h>>3)*8 + {0..7} for group g ----
  {
    int tsub = j >> 3;
    int d8 = (j & 7) * 8;
    #pragma unroll
    for (int ii = 0; ii < 2; ++ii) {
      int tq = (h >> 3) * 8 + ii * 4 + tsub;
      float o0 = 0.f, o1 = 0.f, o2 = 0.f, o3 = 0.f;
      #pragma unroll
      for (int kp4 = 0; kp4 < 8; ++kp4) {
        uint2 a4 = *(const uint2*)(sm + AS_OFF + (tq * 8 + g) * 64 + kp4 * 8);
        float a0 = bflo(a4.x), a1 = bfhi(a4.x), a2 = bflo(a4.y), a3 = bfhi(a4.y);
        #pragma unroll
        for (int c = 0; c < 4; ++c) {
          float ac = (c == 0) ? a0 : (c == 1) ? a1 : (c == 2) ? a2 : a3;
          int row = tq + kp4 * 4 + c;
          uint2 v4 = *(const uint2*)(sm + VS_OFF + ((row * 512 + g * 64 + d8) ^ ((row & 7) << 4)));
          o0 += ac * bflo(v4.x);
          o1 += ac * bfhi(v4.x);
          o2 += ac * bflo(v4.y);
          o3 += ac * bfhi(v4.y);
        }
      }
      *(float4*)(sm + HS_OFF + tq * 1040 + g * 128 + (j & 7) * 16) = make_float4(o0, o1, o2, o3);
    }
  }
  __syncthreads();

  // ---- LN: half-wave h owns t = t0+h; lane owns 8 contiguous d; write h bf16 ----
  float4 x0 = *(const float4*)(sm + HS_OFF + h * 1040 + j * 32);
  float4 x1 = *(const float4*)(sm + HS_OFF + h * 1040 + j * 32 + 16);
  float s1 = x0.x + x0.y + x0.z + x0.w + x1.x + x1.y + x1.z + x1.w;
  float s2 = x0.x * x0.x + x0.y * x0.y + x0.z * x0.z + x0.w * x0.w +
             x1.x * x1.x + x1.y * x1.y + x1.z * x1.z + x1.w * x1.w;
  s1 += __shfl_xor(s1, 16); s2 += __shfl_xor(s2, 16);
  s1 += __shfl_xor(s1, 8);  s2 += __shfl_xor(s2, 8);
  s1 += __shfl_xor(s1, 4);  s2 += __shfl_xor(s2, 4);
  s1 += __shfl_xor(s1, 2);  s2 += __shfl_xor(s2, 2);
  s1 += __shfl_xor(s1, 1);  s2 += __shfl_xor(s2, 1);
  float mu = s1 * (1.f / 256.f);
  float var = s2 * (1.f / 256.f) - mu * mu;
  float inv = rsqrtf(var + LN_EPS);
  float4 ga = *(const float4*)(lng + j * 8);
  float4 gb = *(const float4*)(lng + j * 8 + 4);
  float4 ba = *(const float4*)(lnb + j * 8);
  float4 bb = *(const float4*)(lnb + j * 8 + 4);
  uint4 hp;
  hp.x = (uint)f2bf((x0.x - mu) * inv * ga.x + ba.x) |
         ((uint)f2bf((x0.y - mu) * inv * ga.y + ba.y) << 16);
  hp.y = (uint)f2bf((x0.z - mu) * inv * ga.z + ba.z) |
         ((uint)f2bf((x0.w - mu) * inv * ga.w + ba.w) << 16);
  hp.z = (uint)f2bf((x1.x - mu) * inv * gb.x + bb.x) |
         ((uint)f2bf((x1.y - mu) * inv * gb.y + bb.y) << 16);
  hp.w = (uint)f2bf((x1.z - mu) * inv * gb.z + bb.z) |
         ((uint)f2bf((x1.w - mu) * inv * gb.w + bb.w) << 16);
  *(uint4*)(hB + (bT + t0 + h) * 256 + j * 8) = hp;
}

// ---------- final linear + sigmoid via MFMA: frame[16384][88] ----------
__global__ __launch_bounds__(256) void lin_mfma(const ushort* __restrict__ hB,
                                                const ushort* __restrict__ lwB,
                                                const float* __restrict__ lb,
                                                float* __restrict__ frame) {
  __shared__ ushort As[64 * 40];     // stride 40: conflict-light frag reads
  __shared__ ushort Bs[96 * 264];
  int tid = threadIdx.x;
  int lane = tid & 63, w = tid >> 6;
  int blk = blockIdx.x;
  int l15 = lane & 15, kg = lane >> 4;

  for (int idx = tid; idx < 96 * 32; idx += 256) {
    int o = idx >> 5, c8 = idx & 31;
    uint4 bv = *(const uint4*)(lwB + o * 256 + c8 * 8);
    *(uint4*)(&Bs[o * 264 + c8 * 8]) = bv;
  }

  f32x4 acc[6];
  #pragma unroll
  for (int nf = 0; nf < 6; ++nf) acc[nf] = (f32x4){0.f, 0.f, 0.f, 0.f};

  for (int s = 0; s < 8; ++s) {
    uint4 a0 = {0u, 0u, 0u, 0u}, a1 = {0u, 0u, 0u, 0u};
    if (tid < 128) {
      const ushort* hp = hB + (long)(blk * 64 + (tid >> 1)) * 256 + s * 32 + (tid & 1) * 16;
      a0 = *(const uint4*)(hp);
      a1 = *(const uint4*)(hp + 8);
    }
    __syncthreads();
    if (tid < 128) {
      *(uint4*)(&As[(tid >> 1) * 40 + (tid & 1) * 16]) = a0;
      *(uint4*)(&As[(tid >> 1) * 40 + (tid & 1) * 16 + 8]) = a1;
    }
    __syncthreads();

    short8 af = *(const short8*)(&As[(w * 16 + l15) * 40 + kg * 8]);
    #pragma unroll
    for (int nf = 0; nf < 6; ++nf) {
      short8 bf = *(const short8*)(&Bs[(nf * 16 + l15) * 264 + s * 32 + kg * 8]);
      acc[nf] = __builtin_amdgcn_mfma_f32_16x16x32_bf16(af, bf, acc[nf], 0, 0, 0);
    }
  }

  #pragma unroll
  for (int nf = 0; nf < 6; ++nf) {
    int col = nf * 16 + l15;
    if (col < O_) {
      float bo = lb[col];
      #pragma unroll
      for (int ic = 0; ic < 4; ++ic) {
        int row = blk * 64 + w * 16 + kg * 4 + ic;
        float z = acc[nf][ic] + bo;
        frame[(long)row * O_ + col] = 1.f / (1.f + __expf(-z));
      }
    }
  }
}

extern "C" void kernel_launch(void* const* d_in, const int* in_sizes, int n_in,
                              void* d_out, int out_size, void* d_ws, size_t ws_size,
                              hipStream_t stream) {
  const float* spec = (const float*)d_in[0];
  const float* Wq   = (const float*)d_in[1];
  const float* Wk   = (const float*)d_in[2];
  const float* Wv   = (const float*)d_in[3];
  const float* rel  = (const float*)d_in[4];
  const float* lng  = (const float*)d_in[5];
  const float* lnb  = (const float*)d_in[6];
  const float* lw   = (const float*)d_in[7];
  const float* lb   = (const float*)d_in[8];

  float* out   = (float*)d_out;
  float* frame = out;
  float* attn  = out + (long)B_ * T_ * O_;

  char* ws = (char*)d_ws;
  float*  qb    = (float*)ws;                                // 16 MB
  float*  kb    = (float*)(ws + (16u << 20));                // 16 MB
  ushort* vb    = (ushort*)(ws + (32u << 20));               // 8 MB
  ushort* specB = (ushort*)(ws + (40u << 20));               // 15,204,352 B
  ushort* W2    = (ushort*)(ws + (40u << 20) + 15204352u);   // 786,432 B (absorbs specB tail over-read)
  ushort* lwB   = (ushort*)(ws + (40u << 20) + 15204352u + 786432u);  // 48 KB
  ushort* hB    = specB;                                     // overlay (specB dead after proj)

  conv_spec<<<2048, 256, 0, stream>>>(spec, specB);
  conv_w2<<<768, 256, 0, stream>>>(Wq, Wk, Wv, W2);
  conv_lw<<<96, 256, 0, stream>>>(lw, lwB);
  proj_mfma<<<dim3(128, 6), 256, 0, stream>>>(specB, W2, qb, kb, vb);
  attn4<<<dim3(256, 4), 512, 0, stream>>>(qb, kb, vb, rel, lng, lnb, hB, attn);
  lin_mfma<<<256, 256, 0, stream>>>(hB, lwB, lb, frame);
}